// Round 1
// baseline (554.302 us; speedup 1.0000x reference)
//
#include <hip/hip_runtime.h>
#include <cmath>

typedef __attribute__((ext_vector_type(8))) short bf16x8;
typedef __attribute__((ext_vector_type(4))) float f32x4;
typedef unsigned short u16;

struct __align__(8) us4 { u16 x, y, z, w; };

__device__ __forceinline__ u16 f2bf(float f) {
    union { float f; unsigned u; } v; v.f = f;
    unsigned u = v.u;
    u += 0x7fffu + ((u >> 16) & 1u);   // RNE
    return (u16)(u >> 16);
}
__device__ __forceinline__ float bf2f(u16 h) {
    union { unsigned u; float f; } v; v.u = ((unsigned)h) << 16;
    return v.f;
}
__device__ __forceinline__ f32x4 mfma16(bf16x8 a, bf16x8 b, f32x4 c) {
    return __builtin_amdgcn_mfma_f32_16x16x32_bf16(a, b, c, 0, 0, 0);
}
__device__ __forceinline__ void ld_lds16(const u16* g, u16* l) {
    __builtin_amdgcn_global_load_lds(
        (const __attribute__((address_space(1))) unsigned int*)g,
        (__attribute__((address_space(3))) unsigned int*)l, 16, 0, 0);
}

#define VMCNT(n) asm volatile("s_waitcnt vmcnt(" #n ")" ::: "memory")

// ---------------- x -> CatA right half (bf16) + zero qv/kv ----------------
__global__ __launch_bounds__(256) void cvtx(const float* __restrict__ in,
                                            u16* __restrict__ CatA, float* __restrict__ qkz) {
    int i = blockIdx.x * 256 + threadIdx.x;         // over 3145728 float4 groups
    float4 f = reinterpret_cast<const float4*>(in)[i];
    us4 o; o.x = f2bf(f.x); o.y = f2bf(f.y); o.z = f2bf(f.z); o.w = f2bf(f.w);
    int row = i / 192, col = (i % 192) * 4;
    *reinterpret_cast<us4*>(CatA + (size_t)row * 1536 + 768 + col) = o;
    if (i < 8192) reinterpret_cast<float4*>(qkz)[i] = float4{0.f, 0.f, 0.f, 0.f};
}

// ---------------- 7 weight converts in one dispatch ----------------
struct WCvt { const float* s[7]; u16* d[7]; int ld[7]; };
__global__ __launch_bounds__(256) void cvtw(WCvt w) {
    int wi = blockIdx.y;
    int i = blockIdx.x * 256 + threadIdx.x;         // over 147456 float4 groups
    float4 f = reinterpret_cast<const float4*>(w.s[wi])[i];
    us4 o; o.x = f2bf(f.x); o.y = f2bf(f.y); o.z = f2bf(f.z); o.w = f2bf(f.w);
    int row = i / 192, col = (i % 192) * 4;
    *reinterpret_cast<us4*>(w.d[wi] + (size_t)row * w.ld[wi] + col) = o;
}

// =====================================================================
// 256x192-tile GEMM, BK=32, 8 waves (4M x 2N, 64x96 per wave).
// 4-deep LDS tile pipeline (112 KB): compute tile t, t+1 resident,
// t+2 staging via global_load_lds w16. Steady-state wait is
// s_waitcnt vmcnt(4) -- the queue NEVER drains in the main loop.
// Uniform 4 loads/tile/wave (B rows 128..191 staged twice by paired
// waves, identical data -> benign, keeps vmcnt counting uniform).
// Swizzle for 64B rows: chunk ^= (row>>1)&3 -> 2-way (free) b128 reads.
// Grids: FPT/Y/OUT = 256 blocks, GATES = 512 -> exact CU multiples.
// =====================================================================
enum { EPI_FPT = 0, EPI_Y, EPI_GATES, EPI_OUT };

struct Epi {
    const float* b1; const float* b2; const float* b3; const float* b4;
    const float* wq; const float* wk; float* qv; float* kv;   // FPT
    u16* fpT;
    u16* catA;                                                 // Y
    const u16* xb;        // CatA+768 (stride 1536)
    u16* ub_o; u16* rxb_o;                                     // GATES
    const u16* ub; float* of;                                  // OUT
};

template<int EPI>
__global__ __launch_bounds__(512, 2) void g256(
    const u16* __restrict__ A1, const u16* __restrict__ B1,
    const u16* __restrict__ A2, const u16* __restrict__ B2,
    int nt1, int nt2, int ldA1, int ldB1, int ldA2, int ldB2,
    size_t zA, size_t zB, Epi e)
{
    __shared__ __align__(16) u16 lA[4 * 8192];   // 4 bufs x 256x32 bf16 = 64 KB
    __shared__ __align__(16) u16 lB[4 * 6144];   // 4 bufs x 192x32 bf16 = 48 KB

    const int t = threadIdx.x;
    const int w = t >> 6, lane = t & 63, lm = lane & 15, quad = lane >> 4;
    const int wm = w >> 1, wn = w & 1;           // 4 M-waves x 2 N-waves
    const int row0 = blockIdx.x * 256;
    int col0, grp = 0;
    if constexpr (EPI == EPI_GATES) { grp = blockIdx.y >> 2; col0 = (blockIdx.y & 3) * 192; }
    else col0 = blockIdx.y * 192;

    const u16* A1p = A1 + (size_t)blockIdx.z * zA;
    const u16* B1p = B1 + (size_t)blockIdx.z * zB;
    if constexpr (EPI == EPI_GATES) B1p += (size_t)grp * (768 * 1536);

    const int NT = nt1 + nt2;

    // staging maps: thread t covers (row sr, 16B chunk t&3), source chunk
    // pre-swizzled by (row>>1)&3 so the linear gload_lds dest equals the
    // swizzled layout the reader expects.
    const int sr  = t >> 2;                              // 0..127
    const int sg  = ((t & 3) ^ ((sr >> 1) & 3)) * 8;
    const int srd = (t & 255) >> 2;                      // 0..63 (dup pair)
    const int sgd = ((t & 3) ^ ((srd >> 1) & 3)) * 8;

    auto stageA = [&](int ti) {
        const u16* S; int ld_, k0;
        if (ti < nt1) { S = A1p; ld_ = ldA1; k0 = ti * 32; }
        else          { S = A2;  ld_ = ldA2; k0 = (ti - nt1) * 32; }
        const u16* s0 = S + (size_t)(row0 + sr) * ld_ + k0 + sg;
        u16* d = lA + (ti & 3) * 8192 + w * 512;
        ld_lds16(s0, d);                                  // rows 0..127
        ld_lds16(s0 + (size_t)128 * ld_, d + 4096);       // rows 128..255
    };
    auto stageB = [&](int ti) {
        const u16* S; int ld_, k0;
        if (ti < nt1) { S = B1p; ld_ = ldB1; k0 = ti * 32; }
        else          { S = B2;  ld_ = ldB2; k0 = (ti - nt1) * 32; }
        const u16* s0 = S + (size_t)(col0 + sr) * ld_ + k0 + sg;
        u16* d = lB + (ti & 3) * 6144 + w * 512;
        ld_lds16(s0, d);                                  // rows 0..127
        const u16* s1 = S + (size_t)(col0 + 128 + srd) * ld_ + k0 + sgd;
        ld_lds16(s1, lB + (ti & 3) * 6144 + 4096 + (w & 3) * 512); // rows 128..191 (x2)
    };

    // read-side swizzled fragment offsets (u16 units)
    const int swz  = (quad ^ ((lm >> 1) & 3)) * 8;
    const int aoff = (wm * 64 + lm) * 32 + swz;
    const int boff = (wn * 96 + lm) * 32 + swz;

    f32x4 acc[4][6] = {};

    // prologue: tiles 0 and 1 in flight; wait tile 0 resident (4 newest fly)
    stageA(0); stageB(0); stageA(1); stageB(1);
    VMCNT(4);
    __builtin_amdgcn_s_barrier();

    for (int tt = 0; tt < NT; ++tt) {
        const u16* bufA = lA + (tt & 3) * 8192;
        const u16* bufB = lB + (tt & 3) * 6144;
        const bool pf = (tt + 2) < NT;

        // ---- phase 0: stage A(t+2) | read A + B[0..2] | 12 MFMA ----
        if (pf) stageA(tt + 2);
        bf16x8 a[4], b[3];
#pragma unroll
        for (int i = 0; i < 4; i++) a[i] = *reinterpret_cast<const bf16x8*>(bufA + aoff + i * 512);
#pragma unroll
        for (int j = 0; j < 3; j++) b[j] = *reinterpret_cast<const bf16x8*>(bufB + boff + j * 512);
        __builtin_amdgcn_s_setprio(1);
#pragma unroll
        for (int i = 0; i < 4; i++)
#pragma unroll
            for (int j = 0; j < 3; j++)
                acc[i][j] = mfma16(a[i], b[j], acc[i][j]);
        __builtin_amdgcn_s_setprio(0);
        __builtin_amdgcn_s_barrier();

        // ---- phase 1: stage B(t+2) | read B[3..5] | 12 MFMA ----
        if (pf) stageB(tt + 2);
#pragma unroll
        for (int j = 0; j < 3; j++) b[j] = *reinterpret_cast<const bf16x8*>(bufB + boff + (j + 3) * 512);
        __builtin_amdgcn_s_setprio(1);
#pragma unroll
        for (int i = 0; i < 4; i++)
#pragma unroll
            for (int j = 0; j < 3; j++)
                acc[i][j + 3] = mfma16(a[i], b[j], acc[i][j + 3]);
        __builtin_amdgcn_s_setprio(0);
        if (pf) { VMCNT(4); } else { VMCNT(0); }   // tile tt+1 resident; 4 newest stay in flight
        __builtin_amdgcn_s_barrier();
    }

    // ---------------- epilogue ----------------
    const int rw0 = wm * 64, cw0 = wn * 96;
#pragma unroll
    for (int i = 0; i < 4; i++) {
        const int gr = row0 + rw0 + i * 16 + quad * 4;   // local (per-z) row
        if constexpr (EPI == EPI_FPT) {
            float qp[4] = {}, kp[4] = {};
            const int bb = gr >> 10, nn = gr & 1023;
#pragma unroll
            for (int j = 0; j < 6; j++) {
                const int gc = col0 + cw0 + j * 16 + lm;
                const float bias = e.b1[gc];
                float v0 = acc[i][j][0] + bias, v1 = acc[i][j][1] + bias;
                float v2 = acc[i][j][2] + bias, v3 = acc[i][j][3] + bias;
                us4 o; o.x = f2bf(v0); o.y = f2bf(v1); o.z = f2bf(v2); o.w = f2bf(v3);
                *reinterpret_cast<us4*>(e.fpT + (size_t)bb * 786432 + (size_t)gc * 1024 + nn) = o;
                const float wqv = e.wq[gc], wkv = e.wk[gc];
                qp[0] = fmaf(v0, wqv, qp[0]); qp[1] = fmaf(v1, wqv, qp[1]);
                qp[2] = fmaf(v2, wqv, qp[2]); qp[3] = fmaf(v3, wqv, qp[3]);
                kp[0] = fmaf(v0, wkv, kp[0]); kp[1] = fmaf(v1, wkv, kp[1]);
                kp[2] = fmaf(v2, wkv, kp[2]); kp[3] = fmaf(v3, wkv, kp[3]);
            }
#pragma unroll
            for (int r = 0; r < 4; r++) {
                float q = qp[r], k = kp[r];
#pragma unroll
                for (int m = 1; m < 16; m <<= 1) { q += __shfl_xor(q, m); k += __shfl_xor(k, m); }
                if (lm == 0) { atomicAdd(e.qv + gr + r, q); atomicAdd(e.kv + gr + r, k); }
            }
        } else if constexpr (EPI == EPI_Y) {
            const size_t grow = (size_t)blockIdx.z * 1024 + gr;
#pragma unroll
            for (int j = 0; j < 6; j++) {
                const int gc = col0 + cw0 + j * 16 + lm;
#pragma unroll
                for (int r = 0; r < 4; r++)
                    e.catA[(grow + r) * 1536 + gc] = f2bf(acc[i][j][r]);
            }
        } else if constexpr (EPI == EPI_GATES) {
#pragma unroll
            for (int j = 0; j < 6; j++) {
                const int gc = col0 + cw0 + j * 16 + lm;
                if (grp == 0) {
                    const float bias = e.b1[gc] + e.b2[gc];      // b_uy + b_ux
#pragma unroll
                    for (int r = 0; r < 4; r++) {
                        const size_t idx = (size_t)(gr + r) * 768 + gc;
                        e.ub_o[idx] = f2bf(1.f / (1.f + __expf(-(acc[i][j][r] + bias))));
                    }
                } else {
                    const float bias = e.b3[gc] + e.b4[gc];      // b_ry + b_rx
#pragma unroll
                    for (int r = 0; r < 4; r++) {
                        const size_t idx = (size_t)(gr + r) * 768 + gc;
                        float rr = 1.f / (1.f + __expf(-(acc[i][j][r] + bias)));
                        float xv = bf2f(e.xb[(size_t)(gr + r) * 1536 + gc]);
                        e.rxb_o[idx] = f2bf(rr * xv);
                    }
                }
            }
        } else {  // EPI_OUT: acc = y@Wty + rx@Wtx
#pragma unroll
            for (int j = 0; j < 6; j++) {
                const int gc = col0 + cw0 + j * 16 + lm;
                const float bias = e.b1[gc] + e.b2[gc];          // b_ty + b_tx
#pragma unroll
                for (int r = 0; r < 4; r++) {
                    const size_t idx = (size_t)(gr + r) * 768 + gc;
                    float tv = tanhf(acc[i][j][r] + bias);
                    float uu = bf2f(e.ub[idx]);
                    float xv = bf2f(e.xb[(size_t)(gr + r) * 1536 + gc]);
                    e.of[idx] = (1.f - uu) * xv + uu * tv;
                }
            }
        }
    }
}

// ---------------- softmax: one wave per row, shuffle-only reductions ----------------
__global__ __launch_bounds__(256) void k_soft4(const float* __restrict__ adj,
                                               const float* __restrict__ qv,
                                               const float* __restrict__ kv,
                                               const float* __restrict__ bq,
                                               const float* __restrict__ bk,
                                               u16* __restrict__ attb) {
    int wv = threadIdx.x >> 6, lane = threadIdx.x & 63;
    int bn = blockIdx.x * 4 + wv;
    int b = bn >> 10;
    const float* adjrow = adj + (size_t)bn * 1024 + lane * 16;
    const float* krow = kv + (b << 10) + lane * 16;
    float q = qv[bn] + bq[0] + bk[0];

    float v[16];
#pragma unroll
    for (int c = 0; c < 4; c++) {
        float4 a4 = *reinterpret_cast<const float4*>(adjrow + c * 4);
        float4 k4 = *reinterpret_cast<const float4*>(krow + c * 4);
        float* vv = v + c * 4;
        vv[0] = q + k4.x + (1.f - a4.x) * -1.0e9f;
        vv[1] = q + k4.y + (1.f - a4.y) * -1.0e9f;
        vv[2] = q + k4.z + (1.f - a4.z) * -1.0e9f;
        vv[3] = q + k4.w + (1.f - a4.w) * -1.0e9f;
    }
#pragma unroll
    for (int tt = 0; tt < 16; tt++) v[tt] = v[tt] >= 0.f ? v[tt] : 0.01f * v[tt];

    float mx = v[0];
#pragma unroll
    for (int tt = 1; tt < 16; tt++) mx = fmaxf(mx, v[tt]);
#pragma unroll
    for (int off = 32; off; off >>= 1) mx = fmaxf(mx, __shfl_xor(mx, off));

    float s = 0.f;
#pragma unroll
    for (int tt = 0; tt < 16; tt++) { v[tt] = __expf(v[tt] - mx); s += v[tt]; }
#pragma unroll
    for (int off = 32; off; off >>= 1) s += __shfl_xor(s, off);
    float inv = 1.f / s;

    u16* orow = attb + (size_t)bn * 1024 + lane * 16;
#pragma unroll
    for (int c = 0; c < 4; c++) {
        us4 o;
        o.x = f2bf(v[c * 4 + 0] * inv); o.y = f2bf(v[c * 4 + 1] * inv);
        o.z = f2bf(v[c * 4 + 2] * inv); o.w = f2bf(v[c * 4 + 3] * inv);
        *reinterpret_cast<us4*>(orow + c * 4) = o;
    }
}

extern "C" void kernel_launch(void* const* d_in, const int* in_sizes, int n_in,
                              void* d_out, int out_size, void* d_ws, size_t ws_size,
                              hipStream_t stream) {
    const float* x    = (const float*)d_in[0];
    const float* adj  = (const float*)d_in[1];
    const float* W_fc = (const float*)d_in[2];
    const float* b_fc = (const float*)d_in[3];
    const float* w_q  = (const float*)d_in[4];
    const float* b_q  = (const float*)d_in[5];
    const float* w_k  = (const float*)d_in[6];
    const float* b_k  = (const float*)d_in[7];
    const float* W_uy = (const float*)d_in[8];
    const float* b_uy = (const float*)d_in[9];
    const float* W_ux = (const float*)d_in[10];
    const float* b_ux = (const float*)d_in[11];
    const float* W_ry = (const float*)d_in[12];
    const float* b_ry = (const float*)d_in[13];
    const float* W_rx = (const float*)d_in[14];
    const float* b_rx = (const float*)d_in[15];
    const float* W_ty = (const float*)d_in[16];
    const float* b_ty = (const float*)d_in[17];
    const float* W_tx = (const float*)d_in[18];
    const float* b_tx = (const float*)d_in[19];

    char* ws = (char*)d_ws;
    u16*   CatA  = (u16*)  (ws + 0);            // 16384x1536 bf16  [y | x]   50331648
    u16*   Wfc_b = (u16*)  (ws + 50331648);     //  1179648
    u16*   Wty_b = (u16*)  (ws + 51511296);     //  1179648
    u16*   Wtx_b = (u16*)  (ws + 52690944);     //  1179648
    u16*   Wg    = (u16*)  (ws + 53870592);     // [ [Wuy|Wux] ; [Wry|Wrx] ] 4718592
    u16*   fpT   = (u16*)  (ws + 58589184);     // 16x768x1024 bf16          25165824
    float* qv    = (float*)(ws + 83755008);     // 16384 f32
    float* kv    = (float*)(ws + 83820544);     // 16384 f32
    u16*   attb  = (u16*)  (ws + 83886080);     // 16x1024x1024 bf16         33554432
    u16*   u_b   = (u16*)  (ws + 83886080);     // alias attb (dead after av)
    u16*   rxb   = (u16*)  (ws + 117440512);    // 16384x768 bf16            25165824

    cvtx<<<12288, 256, 0, stream>>>(x, CatA, qv);   // qv,kv contiguous: zeroes both

    WCvt wc;
    wc.s[0] = W_fc; wc.d[0] = Wfc_b;              wc.ld[0] = 768;
    wc.s[1] = W_ty; wc.d[1] = Wty_b;              wc.ld[1] = 768;
    wc.s[2] = W_tx; wc.d[2] = Wtx_b;              wc.ld[2] = 768;
    wc.s[3] = W_uy; wc.d[3] = Wg;                 wc.ld[3] = 1536;
    wc.s[4] = W_ux; wc.d[4] = Wg + 768;           wc.ld[4] = 1536;
    wc.s[5] = W_ry; wc.d[5] = Wg + 768 * 1536;    wc.ld[5] = 1536;
    wc.s[6] = W_rx; wc.d[6] = Wg + 768 * 1536 + 768; wc.ld[6] = 1536;
    cvtw<<<dim3(576, 7), 256, 0, stream>>>(wc);

    Epi e{};
    // feat_proj = x @ Wfc^T + b (A = CatA right half), + fused q/k partials
    e = Epi{}; e.b1 = b_fc; e.wq = w_q; e.wk = w_k; e.qv = qv; e.kv = kv; e.fpT = fpT;
    g256<EPI_FPT><<<dim3(64, 4), 512, 0, stream>>>(CatA + 768, Wfc_b, nullptr, nullptr,
                                                   24, 0, 1536, 768, 0, 0, 0, 0, e);

    k_soft4<<<4096, 256, 0, stream>>>(adj, qv, kv, b_q, b_k, attb);

    // y = att @ fp  -> CatA left half
    e = Epi{}; e.catA = CatA;
    g256<EPI_Y><<<dim3(4, 4, 16), 512, 0, stream>>>(attb, fpT, nullptr, nullptr,
                                                    32, 0, 1024, 1024, 0, 0,
                                                    1048576, 786432, e);
    // gates: [u | r] = CatA @ [Wuy|Wux ; Wry|Wrx]^T
    e = Epi{}; e.b1 = b_uy; e.b2 = b_ux; e.b3 = b_ry; e.b4 = b_rx;
    e.xb = CatA + 768; e.ub_o = u_b; e.rxb_o = rxb;
    g256<EPI_GATES><<<dim3(64, 8), 512, 0, stream>>>(CatA, Wg, nullptr, nullptr,
                                                     48, 0, 1536, 1536, 0, 0, 0, 0, e);
    // out = (1-u)x + u*tanh(y@Wty^T + rx@Wtx^T + b_ty + b_tx)
    e = Epi{}; e.b1 = b_ty; e.b2 = b_tx; e.ub = u_b; e.xb = CatA + 768; e.of = (float*)d_out;
    g256<EPI_OUT><<<dim3(64, 4), 512, 0, stream>>>(CatA, Wty_b, rxb, Wtx_b,
                                                   24, 24, 1536, 768, 768, 768, 0, 0, e);
}

// Round 2
// 477.071 us; speedup vs baseline: 1.1619x; 1.1619x over previous
//
#include <hip/hip_runtime.h>
#include <cmath>

typedef __attribute__((ext_vector_type(8))) short bf16x8;
typedef __attribute__((ext_vector_type(4))) float f32x4;
typedef unsigned short u16;

struct __align__(8) us4 { u16 x, y, z, w; };

__device__ __forceinline__ u16 f2bf(float f) {
    union { float f; unsigned u; } v; v.f = f;
    unsigned u = v.u;
    u += 0x7fffu + ((u >> 16) & 1u);   // RNE
    return (u16)(u >> 16);
}
__device__ __forceinline__ float bf2f(u16 h) {
    union { unsigned u; float f; } v; v.u = ((unsigned)h) << 16;
    return v.f;
}
__device__ __forceinline__ f32x4 mfma16(bf16x8 a, bf16x8 b, f32x4 c) {
    return __builtin_amdgcn_mfma_f32_16x16x32_bf16(a, b, c, 0, 0, 0);
}
__device__ __forceinline__ void ld_lds16(const u16* g, u16* l) {
    __builtin_amdgcn_global_load_lds(
        (const __attribute__((address_space(1))) unsigned int*)g,
        (__attribute__((address_space(3))) unsigned int*)l, 16, 0, 0);
}

#define VMCNT(n) asm volatile("s_waitcnt vmcnt(" #n ")" ::: "memory")

// ---------------- x -> CatA right half (bf16) + zero qv/kv ----------------
__global__ __launch_bounds__(256) void cvtx(const float* __restrict__ in,
                                            u16* __restrict__ CatA, float* __restrict__ qkz) {
    int i = blockIdx.x * 256 + threadIdx.x;         // over 3145728 float4 groups
    float4 f = reinterpret_cast<const float4*>(in)[i];
    us4 o; o.x = f2bf(f.x); o.y = f2bf(f.y); o.z = f2bf(f.z); o.w = f2bf(f.w);
    int row = i / 192, col = (i % 192) * 4;
    *reinterpret_cast<us4*>(CatA + (size_t)row * 1536 + 768 + col) = o;
    if (i < 8192) reinterpret_cast<float4*>(qkz)[i] = float4{0.f, 0.f, 0.f, 0.f};
}

// ---------------- 7 weight converts in one dispatch ----------------
struct WCvt { const float* s[7]; u16* d[7]; int ld[7]; };
__global__ __launch_bounds__(256) void cvtw(WCvt w) {
    int wi = blockIdx.y;
    int i = blockIdx.x * 256 + threadIdx.x;         // over 147456 float4 groups
    float4 f = reinterpret_cast<const float4*>(w.s[wi])[i];
    us4 o; o.x = f2bf(f.x); o.y = f2bf(f.y); o.z = f2bf(f.z); o.w = f2bf(f.w);
    int row = i / 192, col = (i % 192) * 4;
    *reinterpret_cast<us4*>(w.d[wi] + (size_t)row * w.ld[wi] + col) = o;
}

// =====================================================================
// 128x128 GEMM, round-0 structure (4 waves, 256 thr, ~3 blk/CU) with a
// 3-deep rotating LDS pipeline at BK=32 (48 KB): stage(t+2) issues at
// iter top, end-of-iter wait is vmcnt(4) -- the load queue never drains
// in the main loop. Swizzle: chunk ^= (row>>1)&3 on both the staged
// global source and the ds_read address (measured 0 bank conflicts).
// setprio(1) around the MFMA cluster; sched_barrier(0) after each raw
// s_barrier pins the stage below the barrier (buffer-reuse safety).
// =====================================================================
enum { EPI_FPT = 0, EPI_Y, EPI_GATES, EPI_OUT };

struct Epi {
    const float* b1; const float* b2; const float* b3; const float* b4;
    const float* wq; const float* wk; float* qv; float* kv;   // FPT
    u16* fpT;
    u16* catA;                                                 // Y
    const u16* xb;        // CatA+768 (stride 1536)
    u16* ub_o; u16* rxb_o;                                     // GATES
    const u16* ub; float* of;                                  // OUT
};

template<int EPI>
__global__ __launch_bounds__(256) void g128(
    const u16* __restrict__ A1, const u16* __restrict__ B1,
    const u16* __restrict__ A2, const u16* __restrict__ B2,
    int nt1, int nt2, int ldA1, int ldB1, int ldA2, int ldB2,
    size_t zA, size_t zB, Epi e)
{
    __shared__ __align__(16) u16 lA[3 * 4096];   // 3 bufs x 128x32 bf16 = 24 KB
    __shared__ __align__(16) u16 lB[3 * 4096];   // 3 bufs x 128x32 bf16 = 24 KB

    const int t = threadIdx.x;
    const int w = t >> 6, lane = t & 63, lm = lane & 15, quad = lane >> 4;
    const int row0 = blockIdx.x * 128;
    int col0, grp = 0;
    if constexpr (EPI == EPI_GATES) { grp = blockIdx.y / 6; col0 = (blockIdx.y % 6) * 128; }
    else col0 = blockIdx.y * 128;

    const u16* A1p = A1 + (size_t)blockIdx.z * zA;
    const u16* B1p = B1 + (size_t)blockIdx.z * zB;
    if constexpr (EPI == EPI_GATES) B1p += (size_t)grp * (768 * 1536);
    const int NT = nt1 + nt2;

    // staging map: thread t -> row sr = t>>2 (0..63; +64 second round),
    // chunk c = t&3; source chunk pre-swizzled by (row>>1)&3 so the
    // linear global_load_lds dest (base + lane*16) holds the swizzled
    // layout the reader expects.
    const int sr = t >> 2;
    const int sc = ((t & 3) ^ ((sr >> 1) & 3)) * 8;   // u16 units

    auto stage = [&](int ti, int bi) {
        const u16 *Sa, *Sb; int lda_, ldb_, k0;
        if (ti < nt1) { Sa = A1p; Sb = B1p; lda_ = ldA1; ldb_ = ldB1; k0 = ti * 32; }
        else          { Sa = A2;  Sb = B2;  lda_ = ldA2; ldb_ = ldB2; k0 = (ti - nt1) * 32; }
        u16* dA = lA + bi * 4096 + w * 512;
        u16* dB = lB + bi * 4096 + w * 512;
        const u16* ga = Sa + (size_t)(row0 + sr) * lda_ + k0 + sc;
        const u16* gb = Sb + (size_t)(col0 + sr) * ldb_ + k0 + sc;
        ld_lds16(ga, dA);
        ld_lds16(ga + (size_t)64 * lda_, dA + 2048);
        ld_lds16(gb, dB);
        ld_lds16(gb + (size_t)64 * ldb_, dB + 2048);
    };

    // compute map: wave (w&1) row-half, (w>>1) col-half; per-wave 64x64
    const int rw0 = (w & 1) * 64, cw0 = (w >> 1) * 64;
    const int swz = (quad ^ ((lm >> 1) & 3)) * 8;     // read-side swizzle (u16)
    int laB[4], lbB[4];
#pragma unroll
    for (int i = 0; i < 4; i++) laB[i] = (rw0 + i * 16 + lm) * 32 + swz;
#pragma unroll
    for (int j = 0; j < 4; j++) lbB[j] = (cw0 + j * 16 + lm) * 32 + swz;

    f32x4 acc[4][4] = {};

    // prologue: tiles 0,1 in flight (8 loads); wait tile 0 (4 stay in flight)
    stage(0, 0); stage(1, 1);
    VMCNT(4);
    __builtin_amdgcn_s_barrier();
    __builtin_amdgcn_sched_barrier(0);

    int bcur = 0, bpre = 2;                 // tt%3, (tt+2)%3
    for (int tt = 0; tt < NT; ++tt) {
        if (tt + 2 < NT) stage(tt + 2, bpre);

        const u16* bA = lA + bcur * 4096;
        const u16* bB = lB + bcur * 4096;
        bf16x8 a[4], b[4];
#pragma unroll
        for (int i = 0; i < 4; i++) a[i] = *reinterpret_cast<const bf16x8*>(bA + laB[i]);
#pragma unroll
        for (int j = 0; j < 4; j++) b[j] = *reinterpret_cast<const bf16x8*>(bB + lbB[j]);

        __builtin_amdgcn_s_setprio(1);
#pragma unroll
        for (int i = 0; i < 4; i++)
#pragma unroll
            for (int j = 0; j < 4; j++)
                acc[i][j] = mfma16(a[i], b[j], acc[i][j]);
        __builtin_amdgcn_s_setprio(0);

        if (tt + 1 < NT) {
            if (tt + 2 < NT) { VMCNT(4); } else { VMCNT(0); }  // tile tt+1 resident
            __builtin_amdgcn_s_barrier();
            __builtin_amdgcn_sched_barrier(0);
        }
        bcur = (bcur == 2) ? 0 : bcur + 1;
        bpre = (bpre == 2) ? 0 : bpre + 1;
    }

    // ---------------- epilogue (round-0 verified code) ----------------
#pragma unroll
    for (int i = 0; i < 4; i++) {
        const int gr = row0 + rw0 + i * 16 + quad * 4;   // local (per-z) row
        if constexpr (EPI == EPI_FPT) {
            float qp[4] = {}, kp[4] = {};
            int bb = gr >> 10, nn = gr & 1023;
#pragma unroll
            for (int j = 0; j < 4; j++) {
                int gc = col0 + cw0 + j * 16 + lm;
                float bias = e.b1[gc];
                float v0 = acc[i][j][0] + bias, v1 = acc[i][j][1] + bias;
                float v2 = acc[i][j][2] + bias, v3 = acc[i][j][3] + bias;
                us4 o; o.x = f2bf(v0); o.y = f2bf(v1); o.z = f2bf(v2); o.w = f2bf(v3);
                *reinterpret_cast<us4*>(e.fpT + (size_t)bb * 786432 + (size_t)gc * 1024 + nn) = o;
                float wqv = e.wq[gc], wkv = e.wk[gc];
                qp[0] = fmaf(v0, wqv, qp[0]); qp[1] = fmaf(v1, wqv, qp[1]);
                qp[2] = fmaf(v2, wqv, qp[2]); qp[3] = fmaf(v3, wqv, qp[3]);
                kp[0] = fmaf(v0, wkv, kp[0]); kp[1] = fmaf(v1, wkv, kp[1]);
                kp[2] = fmaf(v2, wkv, kp[2]); kp[3] = fmaf(v3, wkv, kp[3]);
            }
#pragma unroll
            for (int r = 0; r < 4; r++) {
                float q = qp[r], k = kp[r];
#pragma unroll
                for (int m = 1; m < 16; m <<= 1) { q += __shfl_xor(q, m); k += __shfl_xor(k, m); }
                if (lm == 0) { atomicAdd(e.qv + gr + r, q); atomicAdd(e.kv + gr + r, k); }
            }
        } else if constexpr (EPI == EPI_Y) {
            size_t grow = (size_t)blockIdx.z * 1024 + gr;
#pragma unroll
            for (int j = 0; j < 4; j++) {
                int gc = col0 + cw0 + j * 16 + lm;
#pragma unroll
                for (int r = 0; r < 4; r++)
                    e.catA[(grow + r) * 1536 + gc] = f2bf(acc[i][j][r]);
            }
        } else if constexpr (EPI == EPI_GATES) {
#pragma unroll
            for (int j = 0; j < 4; j++) {
                int gc = col0 + cw0 + j * 16 + lm;
                if (grp == 0) {
                    float bias = e.b1[gc] + e.b2[gc];      // b_uy + b_ux
#pragma unroll
                    for (int r = 0; r < 4; r++) {
                        size_t idx = (size_t)(gr + r) * 768 + gc;
                        e.ub_o[idx] = f2bf(1.f / (1.f + __expf(-(acc[i][j][r] + bias))));
                    }
                } else {
                    float bias = e.b3[gc] + e.b4[gc];      // b_ry + b_rx
#pragma unroll
                    for (int r = 0; r < 4; r++) {
                        size_t idx = (size_t)(gr + r) * 768 + gc;
                        float rr = 1.f / (1.f + __expf(-(acc[i][j][r] + bias)));
                        float xv = bf2f(e.xb[(size_t)(gr + r) * 1536 + gc]);
                        e.rxb_o[idx] = f2bf(rr * xv);
                    }
                }
            }
        } else {  // EPI_OUT: acc = y@Wty + rx@Wtx
#pragma unroll
            for (int j = 0; j < 4; j++) {
                int gc = col0 + cw0 + j * 16 + lm;
                float bias = e.b1[gc] + e.b2[gc];          // b_ty + b_tx
#pragma unroll
                for (int r = 0; r < 4; r++) {
                    size_t idx = (size_t)(gr + r) * 768 + gc;
                    float tt = tanhf(acc[i][j][r] + bias);
                    float uu = bf2f(e.ub[idx]);
                    float xv = bf2f(e.xb[(size_t)(gr + r) * 1536 + gc]);
                    e.of[idx] = (1.f - uu) * xv + uu * tt;
                }
            }
        }
    }
}

// ---------------- softmax: one wave per row, shuffle-only reductions ----------------
__global__ __launch_bounds__(256) void k_soft4(const float* __restrict__ adj,
                                               const float* __restrict__ qv,
                                               const float* __restrict__ kv,
                                               const float* __restrict__ bq,
                                               const float* __restrict__ bk,
                                               u16* __restrict__ attb) {
    int wv = threadIdx.x >> 6, lane = threadIdx.x & 63;
    int bn = blockIdx.x * 4 + wv;
    int b = bn >> 10;
    const float* adjrow = adj + (size_t)bn * 1024 + lane * 16;
    const float* krow = kv + (b << 10) + lane * 16;
    float q = qv[bn] + bq[0] + bk[0];

    float v[16];
#pragma unroll
    for (int c = 0; c < 4; c++) {
        float4 a4 = *reinterpret_cast<const float4*>(adjrow + c * 4);
        float4 k4 = *reinterpret_cast<const float4*>(krow + c * 4);
        float* vv = v + c * 4;
        vv[0] = q + k4.x + (1.f - a4.x) * -1.0e9f;
        vv[1] = q + k4.y + (1.f - a4.y) * -1.0e9f;
        vv[2] = q + k4.z + (1.f - a4.z) * -1.0e9f;
        vv[3] = q + k4.w + (1.f - a4.w) * -1.0e9f;
    }
#pragma unroll
    for (int t = 0; t < 16; t++) v[t] = v[t] >= 0.f ? v[t] : 0.01f * v[t];

    float mx = v[0];
#pragma unroll
    for (int t = 1; t < 16; t++) mx = fmaxf(mx, v[t]);
#pragma unroll
    for (int off = 32; off; off >>= 1) mx = fmaxf(mx, __shfl_xor(mx, off));

    float s = 0.f;
#pragma unroll
    for (int t = 0; t < 16; t++) { v[t] = __expf(v[t] - mx); s += v[t]; }
#pragma unroll
    for (int off = 32; off; off >>= 1) s += __shfl_xor(s, off);
    float inv = 1.f / s;

    u16* orow = attb + (size_t)bn * 1024 + lane * 16;
#pragma unroll
    for (int c = 0; c < 4; c++) {
        us4 o;
        o.x = f2bf(v[c * 4 + 0] * inv); o.y = f2bf(v[c * 4 + 1] * inv);
        o.z = f2bf(v[c * 4 + 2] * inv); o.w = f2bf(v[c * 4 + 3] * inv);
        *reinterpret_cast<us4*>(orow + c * 4) = o;
    }
}

extern "C" void kernel_launch(void* const* d_in, const int* in_sizes, int n_in,
                              void* d_out, int out_size, void* d_ws, size_t ws_size,
                              hipStream_t stream) {
    const float* x    = (const float*)d_in[0];
    const float* adj  = (const float*)d_in[1];
    const float* W_fc = (const float*)d_in[2];
    const float* b_fc = (const float*)d_in[3];
    const float* w_q  = (const float*)d_in[4];
    const float* b_q  = (const float*)d_in[5];
    const float* w_k  = (const float*)d_in[6];
    const float* b_k  = (const float*)d_in[7];
    const float* W_uy = (const float*)d_in[8];
    const float* b_uy = (const float*)d_in[9];
    const float* W_ux = (const float*)d_in[10];
    const float* b_ux = (const float*)d_in[11];
    const float* W_ry = (const float*)d_in[12];
    const float* b_ry = (const float*)d_in[13];
    const float* W_rx = (const float*)d_in[14];
    const float* b_rx = (const float*)d_in[15];
    const float* W_ty = (const float*)d_in[16];
    const float* b_ty = (const float*)d_in[17];
    const float* W_tx = (const float*)d_in[18];
    const float* b_tx = (const float*)d_in[19];

    char* ws = (char*)d_ws;
    u16*   CatA  = (u16*)  (ws + 0);            // 16384x1536 bf16  [y | x]   50331648
    u16*   Wfc_b = (u16*)  (ws + 50331648);     //  1179648
    u16*   Wty_b = (u16*)  (ws + 51511296);     //  1179648
    u16*   Wtx_b = (u16*)  (ws + 52690944);     //  1179648
    u16*   Wg    = (u16*)  (ws + 53870592);     // [ [Wuy|Wux] ; [Wry|Wrx] ] 4718592
    u16*   fpT   = (u16*)  (ws + 58589184);     // 16x768x1024 bf16          25165824
    float* qv    = (float*)(ws + 83755008);     // 16384 f32
    float* kv    = (float*)(ws + 83820544);     // 16384 f32
    u16*   attb  = (u16*)  (ws + 83886080);     // 16x1024x1024 bf16         33554432
    u16*   u_b   = (u16*)  (ws + 83886080);     // alias attb (dead after av)
    u16*   rxb   = (u16*)  (ws + 117440512);    // 16384x768 bf16            25165824

    cvtx<<<12288, 256, 0, stream>>>(x, CatA, qv);   // qv,kv contiguous: zeroes both

    WCvt wc;
    wc.s[0] = W_fc; wc.d[0] = Wfc_b;              wc.ld[0] = 768;
    wc.s[1] = W_ty; wc.d[1] = Wty_b;              wc.ld[1] = 768;
    wc.s[2] = W_tx; wc.d[2] = Wtx_b;              wc.ld[2] = 768;
    wc.s[3] = W_uy; wc.d[3] = Wg;                 wc.ld[3] = 1536;
    wc.s[4] = W_ux; wc.d[4] = Wg + 768;           wc.ld[4] = 1536;
    wc.s[5] = W_ry; wc.d[5] = Wg + 768 * 1536;    wc.ld[5] = 1536;
    wc.s[6] = W_rx; wc.d[6] = Wg + 768 * 1536 + 768; wc.ld[6] = 1536;
    cvtw<<<dim3(576, 7), 256, 0, stream>>>(wc);

    Epi e{};
    // feat_proj = x @ Wfc^T + b (A = CatA right half), + fused q/k partials
    e = Epi{}; e.b1 = b_fc; e.wq = w_q; e.wk = w_k; e.qv = qv; e.kv = kv; e.fpT = fpT;
    g128<EPI_FPT><<<dim3(128, 6), 256, 0, stream>>>(CatA + 768, Wfc_b, nullptr, nullptr,
                                                    24, 0, 1536, 768, 0, 0, 0, 0, e);

    k_soft4<<<4096, 256, 0, stream>>>(adj, qv, kv, b_q, b_k, attb);

    // y = att @ fp  -> CatA left half
    e = Epi{}; e.catA = CatA;
    g128<EPI_Y><<<dim3(8, 6, 16), 256, 0, stream>>>(attb, fpT, nullptr, nullptr,
                                                    32, 0, 1024, 1024, 0, 0,
                                                    1048576, 786432, e);
    // gates: [u | r] = CatA @ [Wuy|Wux ; Wry|Wrx]^T
    e = Epi{}; e.b1 = b_uy; e.b2 = b_ux; e.b3 = b_ry; e.b4 = b_rx;
    e.xb = CatA + 768; e.ub_o = u_b; e.rxb_o = rxb;
    g128<EPI_GATES><<<dim3(128, 12), 256, 0, stream>>>(CatA, Wg, nullptr, nullptr,
                                                       48, 0, 1536, 1536, 0, 0, 0, 0, e);
    // out = (1-u)x + u*tanh(y@Wty^T + rx@Wtx^T + b_ty + b_tx)
    e = Epi{}; e.b1 = b_ty; e.b2 = b_tx; e.ub = u_b; e.xb = CatA + 768; e.of = (float*)d_out;
    g128<EPI_OUT><<<dim3(128, 6), 256, 0, stream>>>(CatA, Wty_b, rxb, Wtx_b,
                                                    24, 24, 1536, 768, 768, 768, 0, 0, e);
}

// Round 3
// 448.141 us; speedup vs baseline: 1.2369x; 1.0646x over previous
//
#include <hip/hip_runtime.h>
#include <cmath>

typedef __attribute__((ext_vector_type(8))) short bf16x8;
typedef __attribute__((ext_vector_type(4))) float f32x4;
typedef unsigned short u16;

struct __align__(8) us4 { u16 x, y, z, w; };

__device__ __forceinline__ u16 f2bf(float f) {
    union { float f; unsigned u; } v; v.f = f;
    unsigned u = v.u;
    u += 0x7fffu + ((u >> 16) & 1u);   // RNE
    return (u16)(u >> 16);
}
__device__ __forceinline__ float bf2f(u16 h) {
    union { unsigned u; float f; } v; v.u = ((unsigned)h) << 16;
    return v.f;
}
__device__ __forceinline__ f32x4 mfma16(bf16x8 a, bf16x8 b, f32x4 c) {
    return __builtin_amdgcn_mfma_f32_16x16x32_bf16(a, b, c, 0, 0, 0);
}
__device__ __forceinline__ void ld_lds16(const u16* g, u16* l) {
    __builtin_amdgcn_global_load_lds(
        (const __attribute__((address_space(1))) unsigned int*)g,
        (__attribute__((address_space(3))) unsigned int*)l, 16, 0, 0);
}

// ---------------- x -> CatA right half (bf16) + zero qv/kv ----------------
__global__ __launch_bounds__(256) void cvtx(const float* __restrict__ in,
                                            u16* __restrict__ CatA, float* __restrict__ qkz) {
    int i = blockIdx.x * 256 + threadIdx.x;         // over 3145728 float4 groups
    float4 f = reinterpret_cast<const float4*>(in)[i];
    us4 o; o.x = f2bf(f.x); o.y = f2bf(f.y); o.z = f2bf(f.z); o.w = f2bf(f.w);
    int row = i / 192, col = (i % 192) * 4;
    *reinterpret_cast<us4*>(CatA + (size_t)row * 1536 + 768 + col) = o;
    if (i < 8192) reinterpret_cast<float4*>(qkz)[i] = float4{0.f, 0.f, 0.f, 0.f};
}

// ---------------- 7 weight converts in one dispatch ----------------
struct WCvt { const float* s[7]; u16* d[7]; int ld[7]; };
__global__ __launch_bounds__(256) void cvtw(WCvt w) {
    int wi = blockIdx.y;
    int i = blockIdx.x * 256 + threadIdx.x;         // over 147456 float4 groups
    float4 f = reinterpret_cast<const float4*>(w.s[wi])[i];
    us4 o; o.x = f2bf(f.x); o.y = f2bf(f.y); o.z = f2bf(f.z); o.w = f2bf(f.w);
    int row = i / 192, col = (i % 192) * 4;
    *reinterpret_cast<us4*>(w.d[wi] + (size_t)row * w.ld[wi] + col) = o;
}

// =====================================================================
// m97-style GEMM, 128x128 tile, BK=64 — EXACT round-0 main loop
// (measured: GATES 102.8us, MfmaUtil 32%, 0 bank conflicts).
// Change vs round 0: EPI_FPT epilogue transposes the output tile in
// LDS (stride-136 pad, 16B-aligned readback) and stores fpT with
// fully-coalesced 16B chunks along n, instead of 8B scatter at
// stride 2KB (was ~8x write amplification on 24 MB).
// =====================================================================
enum { EPI_FPT = 0, EPI_Y, EPI_GATES, EPI_OUT };

struct Epi {
    const float* b1; const float* b2; const float* b3; const float* b4;
    const float* wq; const float* wk; float* qv; float* kv;   // FPT
    u16* fpT;
    u16* catA;                                                 // Y
    const u16* xb;        // CatA+768 (stride 1536)
    u16* ub_o; u16* rxb_o;                                     // GATES
    const u16* ub; float* of;                                  // OUT
};

template<int EPI, int PH>
__global__ __launch_bounds__(256) void g128(
    const u16* __restrict__ A1, const u16* __restrict__ B1,
    const u16* __restrict__ A2, const u16* __restrict__ B2,
    int K, int ldA1, int ldB1, int ldA2, int ldB2,
    size_t zA, size_t zB, Epi e)
{
    // 34816 B: main loop uses [0,32768) as lA|lB; FPT epilogue reuses the
    // whole buffer as a 128x136 u16 transpose scratch.
    __shared__ __align__(16) u16 shm[17408];
    u16* const lA = shm;
    u16* const lB = shm + 8192;

    const int t = threadIdx.x;
    const int w = t >> 6, lane = t & 63, lm = lane & 15, quad = lane >> 4;
    const int row0 = blockIdx.x * 128;
    int col0, grp = 0;
    if constexpr (EPI == EPI_GATES) { grp = blockIdx.y / 6; col0 = (blockIdx.y % 6) * 128; }
    else col0 = blockIdx.y * 128;

    // staging: linear chunk-id n = q*256 + t; LDS offset = n*16B (fits
    // wave-uniform base + lane*16). Global: row = row0 + q*32 + (t>>3),
    // chunk = (t&7) ^ ((t>>3)&7)  [XOR swizzle vs row&7].
    const int rs2 = t >> 3;                         // 0..31
    const int kc2 = (((t & 7) ^ (rs2 & 7)) * 8);
    u16* dA_[4]; u16* dB_[4];
#pragma unroll
    for (int q = 0; q < 4; q++) {
        dA_[q] = lA + q * 2048 + w * 512;
        dB_[q] = lB + q * 2048 + w * 512;
    }

    // compute map: wave (w&1) row-half, (w>>1) col-half
    const int rw0 = (w & 1) * 64, cw0 = (w >> 1) * 64;
    // LDS read: row R, logical k-half h chunk (quad+4h); stored at chunk^( R&7 ), R&7 == lm&7
    const int ch0 = ((quad) ^ (lm & 7)) * 8;
    const int ch1 = ((quad + 4) ^ (lm & 7)) * 8;
    int laB[4], lbB[4];
#pragma unroll
    for (int i = 0; i < 4; i++) laB[i] = (rw0 + i * 16 + lm) * 64;
#pragma unroll
    for (int j = 0; j < 4; j++) lbB[j] = (cw0 + j * 16 + lm) * 64;

    f32x4 acc[4][4] = {};
    bool first = true;

#pragma unroll
    for (int ph = 0; ph < PH; ph++) {
        const u16* As; const u16* Bs; int ldA, ldB;
        if (ph == 0) { As = A1 + (size_t)blockIdx.z * zA; Bs = B1 + (size_t)blockIdx.z * zB; ldA = ldA1; ldB = ldB1; }
        else         { As = A2; Bs = B2; ldA = ldA2; ldB = ldB2; }
        if constexpr (EPI == EPI_GATES) Bs += (size_t)grp * (768 * 1536);
        const u16* gA = As + (size_t)(row0 + rs2) * ldA + kc2;
        const u16* gB = Bs + (size_t)(col0 + rs2) * ldB + kc2;

        for (int k0 = 0; k0 < K; k0 += 64) {
            if (!first) __syncthreads();
            first = false;
#pragma unroll
            for (int q = 0; q < 4; q++) {
                ld_lds16(gA + (size_t)(q * 32) * ldA + k0, dA_[q]);
                ld_lds16(gB + (size_t)(q * 32) * ldB + k0, dB_[q]);
            }
            __syncthreads();

#pragma unroll
            for (int h = 0; h < 2; h++) {
                const int ch = h ? ch1 : ch0;
                bf16x8 a[4], b[4];
#pragma unroll
                for (int i = 0; i < 4; i++) a[i] = *reinterpret_cast<const bf16x8*>(lA + laB[i] + ch);
#pragma unroll
                for (int j = 0; j < 4; j++) b[j] = *reinterpret_cast<const bf16x8*>(lB + lbB[j] + ch);
#pragma unroll
                for (int i = 0; i < 4; i++)
#pragma unroll
                    for (int j = 0; j < 4; j++)
                        acc[i][j] = mfma16(a[i], b[j], acc[i][j]);
            }
        }
    }

    // ---------------- epilogue ----------------
    if constexpr (EPI == EPI_FPT) __syncthreads();   // LDS reuse safety

#pragma unroll
    for (int i = 0; i < 4; i++) {
        const int gr = row0 + rw0 + i * 16 + quad * 4;   // local (per-z) row
        if constexpr (EPI == EPI_FPT) {
            float qp[4] = {}, kp[4] = {};
            const int nl = rw0 + i * 16 + quad * 4;      // local row in tile
#pragma unroll
            for (int j = 0; j < 4; j++) {
                int gc = col0 + cw0 + j * 16 + lm;
                int dl = cw0 + j * 16 + lm;              // local col in tile
                float bias = e.b1[gc];
                float v0 = acc[i][j][0] + bias, v1 = acc[i][j][1] + bias;
                float v2 = acc[i][j][2] + bias, v3 = acc[i][j][3] + bias;
                us4 o; o.x = f2bf(v0); o.y = f2bf(v1); o.z = f2bf(v2); o.w = f2bf(v3);
                *reinterpret_cast<us4*>(shm + dl * 136 + nl) = o;   // LDS transpose stage
                float wqv = e.wq[gc], wkv = e.wk[gc];
                qp[0] = fmaf(v0, wqv, qp[0]); qp[1] = fmaf(v1, wqv, qp[1]);
                qp[2] = fmaf(v2, wqv, qp[2]); qp[3] = fmaf(v3, wqv, qp[3]);
                kp[0] = fmaf(v0, wkv, kp[0]); kp[1] = fmaf(v1, wkv, kp[1]);
                kp[2] = fmaf(v2, wkv, kp[2]); kp[3] = fmaf(v3, wkv, kp[3]);
            }
#pragma unroll
            for (int r = 0; r < 4; r++) {
                float q = qp[r], k = kp[r];
#pragma unroll
                for (int m = 1; m < 16; m <<= 1) { q += __shfl_xor(q, m); k += __shfl_xor(k, m); }
                if (lm == 0) { atomicAdd(e.qv + gr + r, q); atomicAdd(e.kv + gr + r, k); }
            }
        } else if constexpr (EPI == EPI_Y) {
            size_t grow = (size_t)blockIdx.z * 1024 + gr;
#pragma unroll
            for (int j = 0; j < 4; j++) {
                int gc = col0 + cw0 + j * 16 + lm;
#pragma unroll
                for (int r = 0; r < 4; r++)
                    e.catA[(grow + r) * 1536 + gc] = f2bf(acc[i][j][r]);
            }
        } else if constexpr (EPI == EPI_GATES) {
#pragma unroll
            for (int j = 0; j < 4; j++) {
                int gc = col0 + cw0 + j * 16 + lm;
                if (grp == 0) {
                    float bias = e.b1[gc] + e.b2[gc];      // b_uy + b_ux
#pragma unroll
                    for (int r = 0; r < 4; r++) {
                        size_t idx = (size_t)(gr + r) * 768 + gc;
                        e.ub_o[idx] = f2bf(1.f / (1.f + __expf(-(acc[i][j][r] + bias))));
                    }
                } else {
                    float bias = e.b3[gc] + e.b4[gc];      // b_ry + b_rx
#pragma unroll
                    for (int r = 0; r < 4; r++) {
                        size_t idx = (size_t)(gr + r) * 768 + gc;
                        float rr = 1.f / (1.f + __expf(-(acc[i][j][r] + bias)));
                        float xv = bf2f(e.xb[(size_t)(gr + r) * 1536 + gc]);
                        e.rxb_o[idx] = f2bf(rr * xv);
                    }
                }
            }
        } else {  // EPI_OUT: acc = y@Wty + rx@Wtx
#pragma unroll
            for (int j = 0; j < 4; j++) {
                int gc = col0 + cw0 + j * 16 + lm;
                float bias = e.b1[gc] + e.b2[gc];          // b_ty + b_tx
#pragma unroll
                for (int r = 0; r < 4; r++) {
                    size_t idx = (size_t)(gr + r) * 768 + gc;
                    float tt = tanhf(acc[i][j][r] + bias);
                    float uu = bf2f(e.ub[idx]);
                    float xv = bf2f(e.xb[(size_t)(gr + r) * 1536 + gc]);
                    e.of[idx] = (1.f - uu) * xv + uu * tt;
                }
            }
        }
    }

    // FPT: coalesced transposed store — 128 d-rows x 256B contiguous n
    if constexpr (EPI == EPI_FPT) {
        __syncthreads();
        const int bb = row0 >> 10, nn0 = row0 & 1023;   // tile spans one batch
        const int dl = t >> 1, hf = t & 1;
        const u16* src = shm + dl * 136 + hf * 64;
        u16* dst = e.fpT + (size_t)bb * 786432 + (size_t)(col0 + dl) * 1024 + nn0 + hf * 64;
#pragma unroll
        for (int c = 0; c < 8; c++)
            *reinterpret_cast<bf16x8*>(dst + c * 8) =
                *reinterpret_cast<const bf16x8*>(src + c * 8);
    }
}

// ---------------- softmax: one wave per row, shuffle-only reductions ----------------
__global__ __launch_bounds__(256) void k_soft4(const float* __restrict__ adj,
                                               const float* __restrict__ qv,
                                               const float* __restrict__ kv,
                                               const float* __restrict__ bq,
                                               const float* __restrict__ bk,
                                               u16* __restrict__ attb) {
    int wv = threadIdx.x >> 6, lane = threadIdx.x & 63;
    int bn = blockIdx.x * 4 + wv;
    int b = bn >> 10;
    const float* adjrow = adj + (size_t)bn * 1024 + lane * 16;
    const float* krow = kv + (b << 10) + lane * 16;
    float q = qv[bn] + bq[0] + bk[0];

    float v[16];
#pragma unroll
    for (int c = 0; c < 4; c++) {
        float4 a4 = *reinterpret_cast<const float4*>(adjrow + c * 4);
        float4 k4 = *reinterpret_cast<const float4*>(krow + c * 4);
        float* vv = v + c * 4;
        vv[0] = q + k4.x + (1.f - a4.x) * -1.0e9f;
        vv[1] = q + k4.y + (1.f - a4.y) * -1.0e9f;
        vv[2] = q + k4.z + (1.f - a4.z) * -1.0e9f;
        vv[3] = q + k4.w + (1.f - a4.w) * -1.0e9f;
    }
#pragma unroll
    for (int t = 0; t < 16; t++) v[t] = v[t] >= 0.f ? v[t] : 0.01f * v[t];

    float mx = v[0];
#pragma unroll
    for (int t = 1; t < 16; t++) mx = fmaxf(mx, v[t]);
#pragma unroll
    for (int off = 32; off; off >>= 1) mx = fmaxf(mx, __shfl_xor(mx, off));

    float s = 0.f;
#pragma unroll
    for (int t = 0; t < 16; t++) { v[t] = __expf(v[t] - mx); s += v[t]; }
#pragma unroll
    for (int off = 32; off; off >>= 1) s += __shfl_xor(s, off);
    float inv = 1.f / s;

    u16* orow = attb + (size_t)bn * 1024 + lane * 16;
#pragma unroll
    for (int c = 0; c < 4; c++) {
        us4 o;
        o.x = f2bf(v[c * 4 + 0] * inv); o.y = f2bf(v[c * 4 + 1] * inv);
        o.z = f2bf(v[c * 4 + 2] * inv); o.w = f2bf(v[c * 4 + 3] * inv);
        *reinterpret_cast<us4*>(orow + c * 4) = o;
    }
}

extern "C" void kernel_launch(void* const* d_in, const int* in_sizes, int n_in,
                              void* d_out, int out_size, void* d_ws, size_t ws_size,
                              hipStream_t stream) {
    const float* x    = (const float*)d_in[0];
    const float* adj  = (const float*)d_in[1];
    const float* W_fc = (const float*)d_in[2];
    const float* b_fc = (const float*)d_in[3];
    const float* w_q  = (const float*)d_in[4];
    const float* b_q  = (const float*)d_in[5];
    const float* w_k  = (const float*)d_in[6];
    const float* b_k  = (const float*)d_in[7];
    const float* W_uy = (const float*)d_in[8];
    const float* b_uy = (const float*)d_in[9];
    const float* W_ux = (const float*)d_in[10];
    const float* b_ux = (const float*)d_in[11];
    const float* W_ry = (const float*)d_in[12];
    const float* b_ry = (const float*)d_in[13];
    const float* W_rx = (const float*)d_in[14];
    const float* b_rx = (const float*)d_in[15];
    const float* W_ty = (const float*)d_in[16];
    const float* b_ty = (const float*)d_in[17];
    const float* W_tx = (const float*)d_in[18];
    const float* b_tx = (const float*)d_in[19];

    char* ws = (char*)d_ws;
    u16*   CatA  = (u16*)  (ws + 0);            // 16384x1536 bf16  [y | x]   50331648
    u16*   Wfc_b = (u16*)  (ws + 50331648);     //  1179648
    u16*   Wty_b = (u16*)  (ws + 51511296);     //  1179648
    u16*   Wtx_b = (u16*)  (ws + 52690944);     //  1179648
    u16*   Wg    = (u16*)  (ws + 53870592);     // [ [Wuy|Wux] ; [Wry|Wrx] ] 4718592
    u16*   fpT   = (u16*)  (ws + 58589184);     // 16x768x1024 bf16          25165824
    float* qv    = (float*)(ws + 83755008);     // 16384 f32
    float* kv    = (float*)(ws + 83820544);     // 16384 f32
    u16*   attb  = (u16*)  (ws + 83886080);     // 16x1024x1024 bf16         33554432
    u16*   u_b   = (u16*)  (ws + 83886080);     // alias attb (dead after av)
    u16*   rxb   = (u16*)  (ws + 117440512);    // 16384x768 bf16            25165824

    cvtx<<<12288, 256, 0, stream>>>(x, CatA, qv);   // qv,kv contiguous: zeroes both

    WCvt wc;
    wc.s[0] = W_fc; wc.d[0] = Wfc_b;              wc.ld[0] = 768;
    wc.s[1] = W_ty; wc.d[1] = Wty_b;              wc.ld[1] = 768;
    wc.s[2] = W_tx; wc.d[2] = Wtx_b;              wc.ld[2] = 768;
    wc.s[3] = W_uy; wc.d[3] = Wg;                 wc.ld[3] = 1536;
    wc.s[4] = W_ux; wc.d[4] = Wg + 768;           wc.ld[4] = 1536;
    wc.s[5] = W_ry; wc.d[5] = Wg + 768 * 1536;    wc.ld[5] = 1536;
    wc.s[6] = W_rx; wc.d[6] = Wg + 768 * 1536 + 768; wc.ld[6] = 1536;
    cvtw<<<dim3(576, 7), 256, 0, stream>>>(wc);

    Epi e{};
    // feat_proj = x @ Wfc^T + b (A = CatA right half), + fused q/k partials
    e = Epi{}; e.b1 = b_fc; e.wq = w_q; e.wk = w_k; e.qv = qv; e.kv = kv; e.fpT = fpT;
    g128<EPI_FPT, 1><<<dim3(128, 6), 256, 0, stream>>>(CatA + 768, Wfc_b, nullptr, nullptr,
                                                       768, 1536, 768, 0, 0, 0, 0, e);

    k_soft4<<<4096, 256, 0, stream>>>(adj, qv, kv, b_q, b_k, attb);

    // y = att @ fp  -> CatA left half
    e = Epi{}; e.catA = CatA;
    g128<EPI_Y, 1><<<dim3(8, 6, 16), 256, 0, stream>>>(attb, fpT, nullptr, nullptr,
                                                       1024, 1024, 1024, 0, 0,
                                                       1048576, 786432, e);
    // gates: [u | r] = CatA @ [Wuy|Wux ; Wry|Wrx]^T
    e = Epi{}; e.b1 = b_uy; e.b2 = b_ux; e.b3 = b_ry; e.b4 = b_rx;
    e.xb = CatA + 768; e.ub_o = u_b; e.rxb_o = rxb;
    g128<EPI_GATES, 1><<<dim3(128, 12), 256, 0, stream>>>(CatA, Wg, nullptr, nullptr,
                                                          1536, 1536, 1536, 0, 0, 0, 0, e);
    // out = (1-u)x + u*tanh(y@Wty^T + rx@Wtx^T + b_ty + b_tx)
    e = Epi{}; e.b1 = b_ty; e.b2 = b_tx; e.ub = u_b; e.xb = CatA + 768; e.of = (float*)d_out;
    g128<EPI_OUT, 2><<<dim3(128, 6), 256, 0, stream>>>(CatA, Wty_b, rxb, Wtx_b,
                                                       768, 1536, 768, 768, 768, 0, 0, e);
}